// Round 8
// baseline (20.780 us; speedup 1.0000x reference)
//
#include <hip/hip_runtime.h>
#include <hip/hip_bf16.h>
#include <math.h>

#define EMBED 64
#define BATCH 16384
#define LDH 136        // h1s row stride in bf16 (272B, conflict-free b128)

typedef __attribute__((ext_vector_type(8))) short short8;  // bf16x8 MFMA A/B frag
typedef __attribute__((ext_vector_type(4))) float f32x4;   // MFMA C/D frag

__device__ inline void store_bf16x2(__hip_bfloat16* dst, float x, float y) {
    __hip_bfloat16 tmp[2];
    tmp[0] = __float2bfloat16(x); tmp[1] = __float2bfloat16(y);
    *reinterpret_cast<ushort2*>(dst) = *reinterpret_cast<ushort2*>(tmp);
}

__device__ inline short8 load_w_bf16(const float* p) {
    const float4 lo = reinterpret_cast<const float4*>(p)[0];
    const float4 hi = reinterpret_cast<const float4*>(p)[1];
    __hip_bfloat16 tb[8];
    tb[0] = __float2bfloat16(lo.x); tb[1] = __float2bfloat16(lo.y);
    tb[2] = __float2bfloat16(lo.z); tb[3] = __float2bfloat16(lo.w);
    tb[4] = __float2bfloat16(hi.x); tb[5] = __float2bfloat16(hi.y);
    tb[6] = __float2bfloat16(hi.z); tb[7] = __float2bfloat16(hi.w);
    return *reinterpret_cast<short8*>(tb);
}

// ================= Kernel A: embeddings + attention -> X bf16 =================
// 32 lanes x float2 per batch element -> 2 elements/wave -> 8192 waves
// = 32 waves/CU (full occupancy). No LDS, no barriers.
__global__ __launch_bounds__(256, 8) void gather_attn(
    const int* __restrict__ user, const int* __restrict__ item,
    const int* __restrict__ p1, const int* __restrict__ p2,
    const int* __restrict__ p3, const int* __restrict__ p4, const int* __restrict__ p5,
    const float* __restrict__ Wu, const float* __restrict__ bu,
    const float* __restrict__ Wi, const float* __restrict__ bi,
    __hip_bfloat16* __restrict__ Xb)
{
    const int t    = threadIdx.x;
    const int lane = t & 63;
    const int wv   = t >> 6;
    const int sub  = lane >> 5;        // element within wave (0..1)
    const int el   = lane & 31;        // float2 position within E=64
    const int gb   = blockIdx.x * 8 + wv * 2 + sub;

    const int iu = user[gb];
    const int ii = item[gb];
    int ip[5];
    ip[0] = p1[gb]; ip[1] = p2[gb]; ip[2] = p3[gb]; ip[3] = p4[gb]; ip[4] = p5[gb];

    const float2 bu2 = reinterpret_cast<const float2*>(bu)[el];
    const float2 bi2 = reinterpret_cast<const float2*>(bi)[el];

    // all 7 gathers issue in parallel (dwordx2 each)
    const float2 eu_r = reinterpret_cast<const float2*>(&Wu[(size_t)iu * EMBED])[el];
    const float2 ei_r = reinterpret_cast<const float2*>(&Wi[(size_t)ii * EMBED])[el];
    float2 ep[5];
    #pragma unroll
    for (int k = 0; k < 5; ++k)
        ep[k] = reinterpret_cast<const float2*>(&Wi[(size_t)ip[k] * EMBED])[el];

    float2 eu, ei;
    eu.x = fmaxf(eu_r.x + bu2.x, 0.0f); eu.y = fmaxf(eu_r.y + bu2.y, 0.0f);
    ei.x = fmaxf(ei_r.x + bi2.x, 0.0f); ei.y = fmaxf(ei_r.y + bi2.y, 0.0f);

    float w[5];
    #pragma unroll
    for (int k = 0; k < 5; ++k) {
        ep[k].x = fmaxf(ep[k].x + bi2.x, 0.0f);
        ep[k].y = fmaxf(ep[k].y + bi2.y, 0.0f);
        w[k] = ei.x * ep[k].x + ei.y * ep[k].y;
    }

    // reduce over the 32-lane group: 5 butterfly steps (chains independent over k)
    #pragma unroll
    for (int k = 0; k < 5; ++k) {
        float v = w[k];
        v += __shfl_xor(v, 1, 64);
        v += __shfl_xor(v, 2, 64);
        v += __shfl_xor(v, 4, 64);
        v += __shfl_xor(v, 8, 64);
        v += __shfl_xor(v, 16, 64);
        w[k] = v;
    }

    float m = w[0];
    #pragma unroll
    for (int k = 1; k < 5; ++k) m = fmaxf(m, w[k]);
    float z[5], s = 0.0f;
    #pragma unroll
    for (int k = 0; k < 5; ++k) { z[k] = expf(w[k] - m); s += z[k]; }
    const float scale = 0.2f / s;

    float2 pum = {0.0f, 0.0f};
    #pragma unroll
    for (int k = 0; k < 5; ++k) {
        pum.x += z[k] * ep[k].x;
        pum.y += z[k] * ep[k].y;
    }

    store_bf16x2(&Xb[(size_t)gb * 128 + el * 2],
                 eu.x + scale * pum.x, eu.y + scale * pum.y);
    store_bf16x2(&Xb[(size_t)gb * 128 + 64 + el * 2], ei.x, ei.y);
}

// ================= Kernel B: 3-layer MLP via MFMA =================
// TB=32 rows/block (2 M-tiles), B-fragments loaded once per block.
__global__ __launch_bounds__(256, 2) void mlp_head(
    const __hip_bfloat16* __restrict__ Xb,
    const float* __restrict__ W1, const float* __restrict__ b1v,
    const float* __restrict__ W2, const float* __restrict__ b2v,
    const float* __restrict__ W3, const float* __restrict__ b3,
    float* __restrict__ out)
{
    __shared__ __align__(16) __hip_bfloat16 h1s[32 * LDH];
    __shared__ __align__(16) float          h2s[32 * 68];

    const int t    = threadIdx.x;
    const int lane = t & 63;
    const int wv   = t >> 6;
    const int fr   = lane & 15;    // A row / B col / C col
    const int kg   = lane >> 4;    // k-group
    const int bm   = blockIdx.x * 32;

    // ---------------- Layer 1 ----------------
    const int n0 = wv * 32;
    {
        short8 b1f[2][4];
        #pragma unroll
        for (int tile = 0; tile < 2; ++tile)
            #pragma unroll
            for (int kc = 0; kc < 4; ++kc)
                b1f[tile][kc] = load_w_bf16(&W1[(n0 + tile * 16 + fr) * 128 + kc * 32 + kg * 8]);

        const float bb0 = b1v[n0 + fr];
        const float bb1 = b1v[n0 + 16 + fr];

        #pragma unroll
        for (int mt = 0; mt < 2; ++mt) {
            short8 a[4];
            #pragma unroll
            for (int kc = 0; kc < 4; ++kc)
                a[kc] = *reinterpret_cast<const short8*>(
                    &Xb[(size_t)(bm + mt * 16 + fr) * 128 + kc * 32 + kg * 8]);

            f32x4 c0 = {bb0, bb0, bb0, bb0};
            f32x4 c1 = {bb1, bb1, bb1, bb1};
            #pragma unroll
            for (int kc = 0; kc < 4; ++kc) {
                c0 = __builtin_amdgcn_mfma_f32_16x16x32_bf16(a[kc], b1f[0][kc], c0, 0, 0, 0);
                c1 = __builtin_amdgcn_mfma_f32_16x16x32_bf16(a[kc], b1f[1][kc], c1, 0, 0, 0);
            }

            #pragma unroll
            for (int r = 0; r < 4; ++r) {
                const int row = mt * 16 + kg * 4 + r;
                h1s[row * LDH + n0 + fr]      = __float2bfloat16(fmaxf(c0[r], 0.0f));
                h1s[row * LDH + n0 + 16 + fr] = __float2bfloat16(fmaxf(c1[r], 0.0f));
            }
        }
    }

    __syncthreads();

    // ---------------- Layer 2 ----------------
    const int n2 = wv * 16;
    {
        short8 b2f[4];
        #pragma unroll
        for (int kc = 0; kc < 4; ++kc)
            b2f[kc] = load_w_bf16(&W2[(n2 + fr) * 128 + kc * 32 + kg * 8]);

        const float bb2 = b2v[n2 + fr];

        #pragma unroll
        for (int mt = 0; mt < 2; ++mt) {
            short8 a2[4];
            #pragma unroll
            for (int kc = 0; kc < 4; ++kc)
                a2[kc] = *reinterpret_cast<const short8*>(
                    &h1s[(mt * 16 + fr) * LDH + kc * 32 + kg * 8]);

            f32x4 c2 = {bb2, bb2, bb2, bb2};
            #pragma unroll
            for (int kc = 0; kc < 4; ++kc)
                c2 = __builtin_amdgcn_mfma_f32_16x16x32_bf16(a2[kc], b2f[kc], c2, 0, 0, 0);

            #pragma unroll
            for (int r = 0; r < 4; ++r)
                h2s[(mt * 16 + kg * 4 + r) * 68 + n2 + fr] = fmaxf(c2[r], 0.0f);
        }
    }

    __syncthreads();

    // ---------------- Layer 3 + sigmoid (all 4 waves, 8 rows each) ----------------
    {
        const int bl = wv * 8 + (lane >> 3);   // batch row 0..31
        const int q  = lane & 7;               // k-eighth (8 floats)
        const float4* w3p = reinterpret_cast<const float4*>(&W3[q * 8]);
        const float4* hp  = reinterpret_cast<const float4*>(&h2s[bl * 68 + q * 8]);
        const float4 w0 = w3p[0], w1 = w3p[1];
        const float4 h0 = hp[0],  h1 = hp[1];
        float acc = h0.x * w0.x + h0.y * w0.y + h0.z * w0.z + h0.w * w0.w
                  + h1.x * w1.x + h1.y * w1.y + h1.z * w1.z + h1.w * w1.w;
        acc += __shfl_xor(acc, 1, 64);
        acc += __shfl_xor(acc, 2, 64);
        acc += __shfl_xor(acc, 4, 64);
        if (q == 0)
            out[bm + bl] = 1.0f / (1.0f + expf(-(acc + b3[0])));
    }
}

extern "C" void kernel_launch(void* const* d_in, const int* in_sizes, int n_in,
                              void* d_out, int out_size, void* d_ws, size_t ws_size,
                              hipStream_t stream) {
    const int*   user = (const int*)  d_in[0];
    const int*   item = (const int*)  d_in[1];
    const int*   p1   = (const int*)  d_in[2];
    const int*   p2   = (const int*)  d_in[3];
    const int*   p3   = (const int*)  d_in[4];
    const int*   p4   = (const int*)  d_in[5];
    const int*   p5   = (const int*)  d_in[6];
    const float* Wu   = (const float*)d_in[7];
    const float* bu   = (const float*)d_in[8];
    const float* Wi   = (const float*)d_in[9];
    const float* bi   = (const float*)d_in[10];
    const float* W1   = (const float*)d_in[11];
    const float* b1   = (const float*)d_in[12];
    const float* W2   = (const float*)d_in[13];
    const float* b2   = (const float*)d_in[14];
    const float* W3   = (const float*)d_in[15];
    const float* b3   = (const float*)d_in[16];
    float* out = (float*)d_out;

    __hip_bfloat16* Xb = (__hip_bfloat16*)d_ws;   // 16384 x 128 bf16 = 4 MB

    hipLaunchKernelGGL(gather_attn, dim3(BATCH / 8), dim3(256), 0, stream,
                       user, item, p1, p2, p3, p4, p5, Wu, bu, Wi, bi, Xb);

    hipLaunchKernelGGL(mlp_head, dim3(BATCH / 32), dim3(256), 0, stream,
                       Xb, W1, b1, W2, b2, W3, b3, out);
}

// Round 9
// 15.240 us; speedup vs baseline: 1.3635x; 1.3635x over previous
//
#include <hip/hip_runtime.h>
#include <hip/hip_bf16.h>
#include <math.h>

#define EMBED 64
#define BATCH 16384
#define TB 32          // batch rows per block
#define LDX 136        // bf16 row stride (272B, conflict-free b128)

typedef __attribute__((ext_vector_type(8))) short short8;  // bf16x8 MFMA A/B frag
typedef __attribute__((ext_vector_type(4))) float f32x4;   // MFMA C/D frag

__device__ inline void store_bf16x4(__hip_bfloat16* dst, float4 v) {
    __hip_bfloat16 tmp[4];
    tmp[0] = __float2bfloat16(v.x); tmp[1] = __float2bfloat16(v.y);
    tmp[2] = __float2bfloat16(v.z); tmp[3] = __float2bfloat16(v.w);
    *reinterpret_cast<ushort4*>(dst) = *reinterpret_cast<ushort4*>(tmp);
}

__device__ inline short8 load_w_bf16(const float* p) {
    const float4 lo = reinterpret_cast<const float4*>(p)[0];
    const float4 hi = reinterpret_cast<const float4*>(p)[1];
    __hip_bfloat16 tb[8];
    tb[0] = __float2bfloat16(lo.x); tb[1] = __float2bfloat16(lo.y);
    tb[2] = __float2bfloat16(lo.z); tb[3] = __float2bfloat16(lo.w);
    tb[4] = __float2bfloat16(hi.x); tb[5] = __float2bfloat16(hi.y);
    tb[6] = __float2bfloat16(hi.z); tb[7] = __float2bfloat16(hi.w);
    return *reinterpret_cast<short8*>(tb);
}

// attention compute for one element (16 lanes x float4), given gathered rows
__device__ inline void attn_one(float4 eu_r, float4 ei_r, float4 ep[5],
                                float4 bu4, float4 bi4,
                                __hip_bfloat16* xrow) {
    float4 eu, ei;
    eu.x = fmaxf(eu_r.x + bu4.x, 0.0f); eu.y = fmaxf(eu_r.y + bu4.y, 0.0f);
    eu.z = fmaxf(eu_r.z + bu4.z, 0.0f); eu.w = fmaxf(eu_r.w + bu4.w, 0.0f);
    ei.x = fmaxf(ei_r.x + bi4.x, 0.0f); ei.y = fmaxf(ei_r.y + bi4.y, 0.0f);
    ei.z = fmaxf(ei_r.z + bi4.z, 0.0f); ei.w = fmaxf(ei_r.w + bi4.w, 0.0f);

    float w[5];
    #pragma unroll
    for (int k = 0; k < 5; ++k) {
        ep[k].x = fmaxf(ep[k].x + bi4.x, 0.0f);
        ep[k].y = fmaxf(ep[k].y + bi4.y, 0.0f);
        ep[k].z = fmaxf(ep[k].z + bi4.z, 0.0f);
        ep[k].w = fmaxf(ep[k].w + bi4.w, 0.0f);
        w[k] = ei.x * ep[k].x + ei.y * ep[k].y + ei.z * ep[k].z + ei.w * ep[k].w;
    }

    #pragma unroll
    for (int k = 0; k < 5; ++k) {
        float v = w[k];
        v += __shfl_xor(v, 1, 64);
        v += __shfl_xor(v, 2, 64);
        v += __shfl_xor(v, 4, 64);
        v += __shfl_xor(v, 8, 64);
        w[k] = v;
    }

    float m = w[0];
    #pragma unroll
    for (int k = 1; k < 5; ++k) m = fmaxf(m, w[k]);
    float z[5], s = 0.0f;
    #pragma unroll
    for (int k = 0; k < 5; ++k) { z[k] = __expf(w[k] - m); s += z[k]; }
    const float scale = 0.2f / s;

    float4 pum = {0.0f, 0.0f, 0.0f, 0.0f};
    #pragma unroll
    for (int k = 0; k < 5; ++k) {
        pum.x += z[k] * ep[k].x; pum.y += z[k] * ep[k].y;
        pum.z += z[k] * ep[k].z; pum.w += z[k] * ep[k].w;
    }
    float4 pu;
    pu.x = eu.x + scale * pum.x; pu.y = eu.y + scale * pum.y;
    pu.z = eu.z + scale * pum.z; pu.w = eu.w + scale * pum.w;

    const int el = (threadIdx.x & 63) & 15;
    store_bf16x4(&xrow[el * 4], pu);
    store_bf16x4(&xrow[64 + el * 4], ei);
}

__global__ __launch_bounds__(256, 2) void ncf_fused(
    const int* __restrict__ user, const int* __restrict__ item,
    const int* __restrict__ p1, const int* __restrict__ p2,
    const int* __restrict__ p3, const int* __restrict__ p4, const int* __restrict__ p5,
    const float* __restrict__ Wu, const float* __restrict__ bu,
    const float* __restrict__ Wi, const float* __restrict__ bi,
    const float* __restrict__ W1, const float* __restrict__ b1v,
    const float* __restrict__ W2, const float* __restrict__ b2v,
    const float* __restrict__ W3, const float* __restrict__ b3,
    float* __restrict__ out)
{
    __shared__ __align__(16) __hip_bfloat16 xs [TB * LDX];
    __shared__ __align__(16) __hip_bfloat16 h1s[TB * LDX];
    __shared__ __align__(16) float          h2s[TB * 68];

    const int t    = threadIdx.x;
    const int lane = t & 63;
    const int wv   = t >> 6;       // 0..3
    const int blk  = blockIdx.x;

    const int fr = lane & 15;      // MFMA: A row / B col / C col
    const int kg = lane >> 4;      // MFMA: k-group 0..3
    const int n0 = wv * 32;        // layer-1 cols owned by this wave
    const int n2 = wv * 16;        // layer-2 cols owned by this wave

    // ---------------- Phase 1: issue ALL gathers for both 16-row halves ----------------
    const int sub = lane >> 4;         // element within wave quartet
    const int el  = lane & 15;         // float4 position within E=64
    const int b0  = wv * 4 + sub;      // half 0 row
    const int b1  = 16 + b0;           // half 1 row
    const int gb0 = blk * TB + b0;
    const int gb1 = blk * TB + b1;

    const int iu0 = user[gb0], ii0 = item[gb0];
    const int iu1 = user[gb1], ii1 = item[gb1];
    int ip0[5], ip1[5];
    ip0[0] = p1[gb0]; ip0[1] = p2[gb0]; ip0[2] = p3[gb0]; ip0[3] = p4[gb0]; ip0[4] = p5[gb0];
    ip1[0] = p1[gb1]; ip1[1] = p2[gb1]; ip1[2] = p3[gb1]; ip1[3] = p4[gb1]; ip1[4] = p5[gb1];

    // 14 gathers in flight
    const float4 eu_r0 = reinterpret_cast<const float4*>(&Wu[(size_t)iu0 * EMBED])[el];
    const float4 ei_r0 = reinterpret_cast<const float4*>(&Wi[(size_t)ii0 * EMBED])[el];
    const float4 eu_r1 = reinterpret_cast<const float4*>(&Wu[(size_t)iu1 * EMBED])[el];
    const float4 ei_r1 = reinterpret_cast<const float4*>(&Wi[(size_t)ii1 * EMBED])[el];
    float4 ep0[5], ep1[5];
    #pragma unroll
    for (int k = 0; k < 5; ++k) {
        ep0[k] = reinterpret_cast<const float4*>(&Wi[(size_t)ip0[k] * EMBED])[el];
        ep1[k] = reinterpret_cast<const float4*>(&Wi[(size_t)ip1[k] * EMBED])[el];
    }

    // ---- W1 B-fragment prefetch + cvt: latency/VALU hides under gathers ----
    short8 b1f[2][4];
    #pragma unroll
    for (int tile = 0; tile < 2; ++tile)
        #pragma unroll
        for (int kc = 0; kc < 4; ++kc)
            b1f[tile][kc] = load_w_bf16(&W1[(n0 + tile * 16 + fr) * 128 + kc * 32 + kg * 8]);

    const float4 bu4 = reinterpret_cast<const float4*>(bu)[el];
    const float4 bi4 = reinterpret_cast<const float4*>(bi)[el];

    // compute both halves
    attn_one(eu_r0, ei_r0, ep0, bu4, bi4, &xs[b0 * LDX]);
    attn_one(eu_r1, ei_r1, ep1, bu4, bi4, &xs[b1 * LDX]);

    __syncthreads();

    // ---------------- Layer 1: h1 = relu(X @ W1^T + b1), MFMA ----------------
    {
        const float bb0 = b1v[n0 + fr];
        const float bb1 = b1v[n0 + 16 + fr];

        #pragma unroll
        for (int mt = 0; mt < 2; ++mt) {
            short8 a[4];
            #pragma unroll
            for (int kc = 0; kc < 4; ++kc)
                a[kc] = *reinterpret_cast<const short8*>(
                    &xs[(mt * 16 + fr) * LDX + kc * 32 + kg * 8]);

            f32x4 c0 = {bb0, bb0, bb0, bb0};
            f32x4 c1 = {bb1, bb1, bb1, bb1};
            #pragma unroll
            for (int kc = 0; kc < 4; ++kc) {
                c0 = __builtin_amdgcn_mfma_f32_16x16x32_bf16(a[kc], b1f[0][kc], c0, 0, 0, 0);
                c1 = __builtin_amdgcn_mfma_f32_16x16x32_bf16(a[kc], b1f[1][kc], c1, 0, 0, 0);
            }

            #pragma unroll
            for (int r = 0; r < 4; ++r) {
                const int row = mt * 16 + kg * 4 + r;
                h1s[row * LDX + n0 + fr]      = __float2bfloat16(fmaxf(c0[r], 0.0f));
                h1s[row * LDX + n0 + 16 + fr] = __float2bfloat16(fmaxf(c1[r], 0.0f));
            }
        }
    }

    // W2 fragment loads proceed while waiting at the barrier
    short8 b2f[4];
    #pragma unroll
    for (int kc = 0; kc < 4; ++kc)
        b2f[kc] = load_w_bf16(&W2[(n2 + fr) * 128 + kc * 32 + kg * 8]);

    __syncthreads();

    // ---------------- Layer 2: h2 = relu(H1 @ W2^T + b2), MFMA ----------------
    {
        const float bb2 = b2v[n2 + fr];

        #pragma unroll
        for (int mt = 0; mt < 2; ++mt) {
            short8 a2[4];
            #pragma unroll
            for (int kc = 0; kc < 4; ++kc)
                a2[kc] = *reinterpret_cast<const short8*>(
                    &h1s[(mt * 16 + fr) * LDX + kc * 32 + kg * 8]);

            f32x4 c2 = {bb2, bb2, bb2, bb2};
            #pragma unroll
            for (int kc = 0; kc < 4; ++kc)
                c2 = __builtin_amdgcn_mfma_f32_16x16x32_bf16(a2[kc], b2f[kc], c2, 0, 0, 0);

            #pragma unroll
            for (int r = 0; r < 4; ++r)
                h2s[(mt * 16 + kg * 4 + r) * 68 + n2 + fr] = fmaxf(c2[r], 0.0f);
        }
    }

    __syncthreads();

    // ---------------- Layer 3 + sigmoid (all 4 waves, 8 rows each) ----------------
    {
        const int bl = wv * 8 + (lane >> 3);   // batch row 0..31
        const int q  = lane & 7;               // k-eighth
        const float4* w3p = reinterpret_cast<const float4*>(&W3[q * 8]);
        const float4* hp  = reinterpret_cast<const float4*>(&h2s[bl * 68 + q * 8]);
        const float4 w0 = w3p[0], w1 = w3p[1];
        const float4 h0 = hp[0],  h1 = hp[1];
        float acc = h0.x * w0.x + h0.y * w0.y + h0.z * w0.z + h0.w * w0.w
                  + h1.x * w1.x + h1.y * w1.y + h1.z * w1.z + h1.w * w1.w;
        acc += __shfl_xor(acc, 1, 64);
        acc += __shfl_xor(acc, 2, 64);
        acc += __shfl_xor(acc, 4, 64);
        if (q == 0)
            out[blk * TB + bl] = 1.0f / (1.0f + __expf(-(acc + b3[0])));
    }
}

extern "C" void kernel_launch(void* const* d_in, const int* in_sizes, int n_in,
                              void* d_out, int out_size, void* d_ws, size_t ws_size,
                              hipStream_t stream) {
    const int*   user = (const int*)  d_in[0];
    const int*   item = (const int*)  d_in[1];
    const int*   p1   = (const int*)  d_in[2];
    const int*   p2   = (const int*)  d_in[3];
    const int*   p3   = (const int*)  d_in[4];
    const int*   p4   = (const int*)  d_in[5];
    const int*   p5   = (const int*)  d_in[6];
    const float* Wu   = (const float*)d_in[7];
    const float* bu   = (const float*)d_in[8];
    const float* Wi   = (const float*)d_in[9];
    const float* bi   = (const float*)d_in[10];
    const float* W1   = (const float*)d_in[11];
    const float* b1   = (const float*)d_in[12];
    const float* W2   = (const float*)d_in[13];
    const float* b2   = (const float*)d_in[14];
    const float* W3   = (const float*)d_in[15];
    const float* b3   = (const float*)d_in[16];
    float* out = (float*)d_out;

    hipLaunchKernelGGL(ncf_fused, dim3(BATCH / TB), dim3(256), 0, stream,
                       user, item, p1, p2, p3, p4, p5,
                       Wu, bu, Wi, bi, W1, b1, W2, b2, W3, b3, out);
}